// Round 15
// baseline (1546.424 us; speedup 1.0000x reference)
//
#include <hip/hip_runtime.h>
#include <cstdio>
#include <cstdint>

typedef _Float16 f16;
typedef f16 hf2   __attribute__((ext_vector_type(2)));
typedef f16 f16x8 __attribute__((ext_vector_type(8)));
typedef float f32x4 __attribute__((ext_vector_type(4)));
typedef unsigned int   u32;
typedef unsigned short u16;

#define B_    256
#define S_    512
#define IN_   32
#define H_    256
#define G3_   768
#define D_    32
#define PRED_ 96
#define TC_   32     // in-kernel time sub-chunk (steps per LDS stage)
#define HP_   136    // padded h k-slice (halves): 128 data + 8 pad (bank shift)

#if __has_builtin(__builtin_amdgcn_fdot2)
__device__ __forceinline__ float fdot2(hf2 a, hf2 b, float c) {
  return __builtin_amdgcn_fdot2(a, b, c, false);
}
#else
__device__ __forceinline__ float fdot2(hf2 a, hf2 b, float c) {
  return c + (float)a[0] * (float)b[0] + (float)a[1] * (float)b[1];
}
#endif

// DPP cross-lane add on the VALU pipe (round-12: replacing LDS-pipe shuffles
// with these was +18 us/dispatch).
__device__ __forceinline__ float dpp_add_xor1(float x) {
  int y = __builtin_amdgcn_mov_dpp(__builtin_bit_cast(int, x), 0xB1, 0xF, 0xF, true);
  return x + __builtin_bit_cast(float, y);   // quad_perm [1,0,3,2]
}

__device__ __forceinline__ float sigm(float x) {
  return __builtin_amdgcn_rcpf(1.f + __expf(-x));
}
__device__ __forceinline__ float tanh_fast(float x) {
  return 1.f - 2.f * __builtin_amdgcn_rcpf(__expf(2.f * x) + 1.f);
}
__device__ __forceinline__ hf2 bc2(u32 v) { return __builtin_bit_cast(hf2, v); }

__global__ void f32_to_f16_k(const float* __restrict__ in, f16* __restrict__ out, int n) {
  int i = blockIdx.x * blockDim.x + threadIdx.x;
  if (i < n) out[i] = (f16)in[i];
}

// biasc[n] = bih[n] + (n<512 ? bhh[n] : 0)  — r,z gate bhh folded into xp.
__global__ void make_bias(const float* __restrict__ bih, const float* __restrict__ bhh,
                          float* __restrict__ out) {
  int i = blockIdx.x * blockDim.x + threadIdx.x;
  if (i < G3_) out[i] = bih[i] + (i < 512 ? bhh[i] : 0.f);
}

__device__ __forceinline__ f16x8 cvt8(const float* p) {
  float4 lo = ((const float4*)p)[0];
  float4 hi = ((const float4*)p)[1];
  f16x8 r;
  r[0] = (f16)lo.x; r[1] = (f16)lo.y; r[2] = (f16)lo.z; r[3] = (f16)lo.w;
  r[4] = (f16)hi.x; r[5] = (f16)hi.y; r[6] = (f16)hi.z; r[7] = (f16)hi.w;
  return r;
}

// ------- chunked xp GEMM: xp_chunk = A_chunk @ Wih^T + biasc (f16 out) ------
template <int KK>   // 32: A = f32 x;  256: A = f16 (h1 chunk)
__global__ __launch_bounds__(256) void gemm_xp(
    const void* __restrict__ Asrc, size_t aBlk, int tl_rows,
    const f16* __restrict__ Wih,     // f16 [768][KK]
    const float* __restrict__ biasc, // [768]
    u16* __restrict__ xp) {          // chunk-local [B*tl_rows][768] f16
  const int tid = threadIdx.x;
  const int wv = tid >> 6, lane = tid & 63, lm = lane & 15, q = lane >> 4;
  const int tiles_pb = tl_rows >> 6;
  const int b = blockIdx.x / tiles_pb, hf = blockIdx.x % tiles_pb;
  const size_t arow0 = (size_t)b * aBlk + (size_t)(hf * 64) * KK;
  const size_t orow0 = (size_t)b * tl_rows + hf * 64;

#pragma unroll 1
  for (int nt = 0; nt < 12; ++nt) {
    const int n0 = wv * 192 + nt * 16;
    const f16* Bp = Wih + (size_t)(n0 + lm) * KK + q * 8;
    f32x4 acc[4];
#pragma unroll
    for (int j = 0; j < 4; ++j) acc[j] = f32x4{0.f, 0.f, 0.f, 0.f};
#pragma unroll
    for (int k0 = 0; k0 < KK; k0 += 32) {
      f16x8 bv = *(const f16x8*)(Bp + k0);
#pragma unroll
      for (int j = 0; j < 4; ++j) {
        f16x8 av;
        if constexpr (KK == 32) {
          av = cvt8((const float*)Asrc + arow0 + (size_t)(j * 16 + lm) * KK + k0 + q * 8);
        } else {
          av = *(const f16x8*)((const f16*)Asrc + arow0 + (size_t)(j * 16 + lm) * KK + k0 + q * 8);
        }
        acc[j] = __builtin_amdgcn_mfma_f32_16x16x32_f16(av, bv, acc[j], 0, 0, 0);
      }
    }
    const float bb = biasc[n0 + lm];
#pragma unroll
    for (int j = 0; j < 4; ++j)
#pragma unroll
      for (int r = 0; r < 4; ++r)   // D: col=lane&15 (n), row=q*4+r (m)
        xp[(orow0 + j * 16 + q * 4 + r) * G3_ + n0 + lm] =
            __builtin_bit_cast(u16, (f16)(acc[j][r] + bb));
  }
}

// ---------------- pure-VALU recurrence kernel (768 thr, gate-partition) -----
// One WG (768 thr, 12 waves, 3/SIMD) per batch row.
// Thread t = (g = t>>8, i = t&255); kh = i&1, up = i>>1 -> units {2up, 2up+1},
// ONE gate g, k-slice [kh*128, kh*128+128).
// Per-thread stationary W = 2 units x 1 gate x 128 halves = 512B = 128 VGPRs.
// WHY: at 512 thr any full-residency partition needs 393KB/512 = 768B = 192
// VGPRs/thread, but the allocator grants ~120 -> ~72 dwords AGPR-parked ->
// ~72 v_accvgpr_read per thread per step (the measured 3x VALU inflation,
// rounds 7-12). At 768 thr the invariant drops to 128 regs, inside the
// 512/3=170 budget -> AGPR tax ~0. Same MACs/thread (128 dot2).
// Gate recombination: 1 DPP pair-add, then pa[768] LDS exchange; h-update by
// threads t<256. Two barriers/step.
template <int LAYER>
__global__ __launch_bounds__(768, 3) void gru_rec(
    const u16* __restrict__ xp,      // chunk-local [B*tl_rows][768] f16
    const f16* __restrict__ Whh16,   // f16 [768][256]
    const float* __restrict__ bhh,   // [768] (n-gate slice used)
    float* __restrict__ hstate,      // f32 [B][256], in+out across chunks
    f16* __restrict__ h1c,           // chunk-local [B*tl_rows][256] (LAYER==0)
    int tl_rows, int first) {
  const int b   = blockIdx.x;
  const int tid = threadIdx.x;
  const int g  = tid >> 8;           // gate 0=r 1=z 2=n (wave-uniform: 256=4 waves)
  const int i  = tid & 255;
  const int kh = i & 1, up = i >> 1;
  const int u0 = up * 2;

  // ---- W_hh -> registers (once): 2 units x 16 uint4 = 32 uint4 = 128 VGPRs --
  uint4 w0[16], w1[16];
  {
    const uint4* r0 = (const uint4*)Whh16 + (size_t)(g * 256 + u0) * 32 + kh * 16;
    const uint4* r1 = (const uint4*)Whh16 + (size_t)(g * 256 + u0 + 1) * 32 + kh * 16;
#pragma unroll
    for (int t = 0; t < 16; ++t) { w0[t] = r0[t]; w1[t] = r1[t]; }
  }
  const float bhn = (tid < 256) ? bhh[512 + tid] : 0.f;

  __shared__ u16 xbuf[2][TC_ * G3_];              // 98,304 B
  __shared__ __align__(16) u16 hbuf[2][2 * HP_];  // 1,088 B (padded k-slices)
  __shared__ float pa[G3_];                       // 3,072 B (pre-act exchange)
  __shared__ u16 hhist[TC_ * H_];                 // 16,384 B

  float h = 0.f;
  if (tid < 256) {
    h = first ? 0.f : hstate[b * H_ + tid];
    hbuf[0][(tid >> 7) * HP_ + (tid & 127)] = __builtin_bit_cast(u16, (f16)h);
  }
  int cur = 0;
  const uint4* xsrc = (const uint4*)xp + (size_t)b * tl_rows * 96;  // 96 uint4/row
  const int nsub = tl_rows >> 5;

#pragma unroll 1
  for (int c2 = 0; c2 < nsub; ++c2) {
    // ---- stage sub-chunk: 48KB = 3072 uint4, 2 passes x 2/thread ----
    {
      const uint4* src = xsrc + (size_t)c2 * 3072;
      uint4* dst = (uint4*)xbuf[c2 & 1];
#pragma unroll
      for (int pass = 0; pass < 2; ++pass) {
        uint4 v0 = src[(pass * 2 + 0) * 768 + tid];
        uint4 v1 = src[(pass * 2 + 1) * 768 + tid];
        dst[(pass * 2 + 0) * 768 + tid] = v0;
        dst[(pass * 2 + 1) * 768 + tid] = v1;
      }
    }
    __syncthreads();   // xbuf visible; also covers hbuf[0] init / prior writes
    const u16* xrow0 = xbuf[c2 & 1];

#pragma unroll 1
    for (int tl = 0; tl < TC_; ++tl) {
      // kh's k-slice of h: 16 uint4 at padded offset kh*HP_ halves
      const uint4* hb = (const uint4*)(hbuf[cur] + kh * HP_);
      float a0 = 0.f, a1 = 0.f, a0b = 0.f, a1b = 0.f;
#pragma unroll
      for (int cc = 0; cc < 16; ++cc) {
        uint4 hv = hb[cc];
        uint4 wa = w0[cc], wb = w1[cc];
        a0  = fdot2(bc2(wa.x), bc2(hv.x), a0);
        a1  = fdot2(bc2(wb.x), bc2(hv.x), a1);
        a0b = fdot2(bc2(wa.y), bc2(hv.y), a0b);
        a1b = fdot2(bc2(wb.y), bc2(hv.y), a1b);
        a0  = fdot2(bc2(wa.z), bc2(hv.z), a0);
        a1  = fdot2(bc2(wb.z), bc2(hv.z), a1);
        a0b = fdot2(bc2(wa.w), bc2(hv.w), a0b);
        a1b = fdot2(bc2(wb.w), bc2(hv.w), a1b);
      }
      a0 += a0b; a1 += a1b;
      // kh-pair reduction (lanes i, i^1 adjacent): both lanes get full sums
      a0 = dpp_add_xor1(a0);
      a1 = dpp_add_xor1(a1);
      // thread kh writes unit u0+kh's pre-act: pa[g*256 + i] == pa[tid]
      pa[tid] = kh ? a1 : a0;
      __syncthreads();   // pre-acts visible

      if (tid < 256) {   // h-update: thread u = tid
        const int u = tid;
        const u16* xrow = xrow0 + tl * G3_;
        float xr = (float)__builtin_bit_cast(f16, xrow[u]);
        float xz = (float)__builtin_bit_cast(f16, xrow[256 + u]);
        float xn = (float)__builtin_bit_cast(f16, xrow[512 + u]);
        float r = sigm(xr + pa[u]);              // bhh_r folded into xp
        float z = sigm(xz + pa[256 + u]);        // bhh_z folded into xp
        float n = tanh_fast(xn + r * (pa[512 + u] + bhn));
        h = n + z * (h - n);
        const u16 h16v = __builtin_bit_cast(u16, (f16)h);
        hbuf[cur ^ 1][(u >> 7) * HP_ + (u & 127)] = h16v;
        if constexpr (LAYER == 0) hhist[tl * H_ + u] = h16v;
      }
      __syncthreads();   // h(t+1) visible; pa free for rewrite
      cur ^= 1;
    }

    if constexpr (LAYER == 0) {
      // coalesced sub-chunk flush: 16KB = 1024 uint4, threads 0..511 x2
      if (tid < 512) {
        uint4 hv0 = ((const uint4*)hhist)[tid];
        uint4 hv1 = ((const uint4*)hhist)[512 + tid];
        uint4* dst = (uint4*)(h1c + ((size_t)b * tl_rows + c2 * TC_) * H_);
        dst[tid] = hv0;
        dst[512 + tid] = hv1;
      }
    }
  }
  if (tid < 256) hstate[b * H_ + tid] = h;
}

// ---------------- projection + 96-step rollout ------------------------------
__global__ __launch_bounds__(128) void proj_rollout(
    const float* __restrict__ hfinal, const float* __restrict__ Wp,
    const float* __restrict__ bp, const float* __restrict__ Cm,
    const float* __restrict__ rld, const float* __restrict__ rtd,
    const float* __restrict__ rg, const float* __restrict__ om,
    float* __restrict__ out) {
  const int b = blockIdx.x, tid = threadIdx.x;
  __shared__ float fh[256];
  __shared__ float sb[128];
  ((float2*)fh)[tid] = ((const float2*)(hfinal + b * 256))[tid];
  __syncthreads();
  const float4* wrow = (const float4*)(Wp + tid * 256);
  float acc = 0.f;
#pragma unroll 16
  for (int k4 = 0; k4 < 64; k4++) {
    float4 wv = wrow[k4];
    acc += wv.x * fh[4 * k4] + wv.y * fh[4 * k4 + 1] + wv.z * fh[4 * k4 + 2] +
           wv.w * fh[4 * k4 + 3];
  }
  sb[tid] = acc + bp[tid];
  __syncthreads();
  if (tid < 32) {
    const int dd = tid;
    float s0 = sb[dd * 4], s1 = sb[dd * 4 + 1], s2 = sb[dd * 4 + 2], s3 = sb[dd * 4 + 3];
    float al = sigm(rld[dd]) * 0.15f + 0.85f;
    float at = sigm(rtd[dd]) * 0.25f + 0.70f;
    float g  = sigm(rg[dd]) * 0.20f + 0.80f;
    float cw = cosf(om[dd]), sw = sinf(om[dd]);
    float r00 = g * cw, r01 = -g * sw, r10 = g * sw, r11 = g * cw;
    float c0 = Cm[dd * 4], c1 = Cm[dd * 4 + 1], c2 = Cm[dd * 4 + 2], c3 = Cm[dd * 4 + 3];
    float* op = out + (size_t)b * PRED_ * D_ + dd;
    for (int t = 0; t < PRED_; t++) {
      float n0 = s0 * al, n1 = s1 * at;
      float n2 = s2 * r00 + s3 * r10;
      float n3 = s2 * r01 + s3 * r11;
      op[(size_t)t * D_] = c0 * n0 + c1 * n1 + c2 * n2 + c3 * n3;
      s0 = n0; s1 = n1; s2 = n2; s3 = n3;
    }
  }
}

extern "C" void kernel_launch(void* const* d_in, const int* in_sizes, int n_in,
                              void* d_out, int out_size, void* d_ws,
                              size_t ws_size, hipStream_t stream) {
  (void)in_sizes; (void)n_in; (void)out_size;
  const float* x     = (const float*)d_in[0];
  const float* Wih0  = (const float*)d_in[1];
  const float* Whh0  = (const float*)d_in[2];
  const float* bih0  = (const float*)d_in[3];
  const float* bhh0  = (const float*)d_in[4];
  const float* Wih1  = (const float*)d_in[5];
  const float* Whh1  = (const float*)d_in[6];
  const float* bih1  = (const float*)d_in[7];
  const float* bhh1  = (const float*)d_in[8];
  const float* Wproj = (const float*)d_in[9];
  const float* bproj = (const float*)d_in[10];
  const float* Cm    = (const float*)d_in[11];
  const float* rld   = (const float*)d_in[12];
  const float* rtd   = (const float*)d_in[13];
  const float* rg    = (const float*)d_in[14];
  const float* om    = (const float*)d_in[15];
  float* out = (float*)d_out;

  char* ws = (char*)d_ws;
  // fixed region
  const size_t wi0_off  = 0;           //    49,152
  const size_t wi1_off  = 49152;       //   393,216
  const size_t whh0_off = 442368;      //   393,216
  const size_t whh1_off = 835584;      //   393,216
  const size_t b0_off   = 1228800;     //     3,072
  const size_t b1_off   = 1231872;     //     3,072
  const size_t hs0_off  = 1234944;     //   262,144 (f32 [B][256])
  const size_t hs1_off  = 1497088;     //   262,144
  const size_t h1c_off  = 1759232;     // h1 chunk: B*TL*256*2
  const size_t need64  = h1c_off + (size_t)B_ * 64 * H_ * 2  + (size_t)B_ * 64 * G3_ * 2;
  const size_t need128 = h1c_off + (size_t)B_ * 128 * H_ * 2 + (size_t)B_ * 128 * G3_ * 2;

  if (ws_size < need64) {
    fprintf(stderr, "kernel_launch: ws too small: have %zu need %zu — skipping\n",
            ws_size, need64);
    return;
  }
  const int TL = (ws_size >= need128) ? 128 : 64;
  const size_t xpc_off = h1c_off + (size_t)B_ * TL * H_ * 2;

  f16* wi016   = (f16*)(ws + wi0_off);
  f16* wi116   = (f16*)(ws + wi1_off);
  f16* whh016  = (f16*)(ws + whh0_off);
  f16* whh116  = (f16*)(ws + whh1_off);
  float* bias0 = (float*)(ws + b0_off);
  float* bias1 = (float*)(ws + b1_off);
  float* hst0  = (float*)(ws + hs0_off);
  float* hst1  = (float*)(ws + hs1_off);
  f16* h1c     = (f16*)(ws + h1c_off);
  u16* xpc     = (u16*)(ws + xpc_off);

  f32_to_f16_k<<<96, 256, 0, stream>>>(Wih0, wi016, G3_ * IN_);
  f32_to_f16_k<<<768, 256, 0, stream>>>(Wih1, wi116, G3_ * H_);
  f32_to_f16_k<<<768, 256, 0, stream>>>(Whh0, whh016, G3_ * H_);
  f32_to_f16_k<<<768, 256, 0, stream>>>(Whh1, whh116, G3_ * H_);
  make_bias<<<3, 256, 0, stream>>>(bih0, bhh0, bias0);
  make_bias<<<3, 256, 0, stream>>>(bih1, bhh1, bias1);

  const int nchunks = S_ / TL;
  const int gblocks = B_ * (TL / 64);
  for (int c = 0; c < nchunks; ++c) {
    gemm_xp<IN_><<<gblocks, 256, 0, stream>>>(
        (const void*)(x + (size_t)c * TL * IN_), (size_t)S_ * IN_, TL, wi016, bias0, xpc);
    gru_rec<0><<<B_, 768, 0, stream>>>(xpc, whh016, bhh0, hst0, h1c, TL, c == 0);
    gemm_xp<H_><<<gblocks, 256, 0, stream>>>(
        (const void*)h1c, (size_t)TL * H_, TL, wi116, bias1, xpc);
    gru_rec<1><<<B_, 768, 0, stream>>>(xpc, whh116, bhh1, hst1, nullptr, TL, c == 0);
  }
  proj_rollout<<<B_, 128, 0, stream>>>(hst1, Wproj, bproj, Cm, rld, rtd, rg, om, out);
}